// Round 8
// baseline (158.323 us; speedup 1.0000x reference)
//
#include <hip/hip_runtime.h>
#include <math.h>

#define NMEL   40
#define NCEP   13
#define BATCH  1024
#define NSAMP  16000
#define NFRAME 49
#define PI_F   3.14159265358979323846f

// d_ws float layout
#define WS_WIN  0        // 640 floats: Hann window (kept for layout compat)
#define WS_R    640      // 512 float2: W_1024^k (kept for layout compat)
#define WS_DT   1664     // 520 floats: DCT * 1/sqrt(80) * lifter, [40][13]
#define WS_BT   2184     // f16 area: Bt[48][544] mel weights transposed
#define WS_TOT  15240
#define SENT0   0x4D464343u
#define SENT1   0x9A7C55E1u

// exact power-of-2 reciprocals
#define INV16    0.0625f
#define INV32    0.03125f
#define INV64    0.015625f
#define INV128   0.0078125f
#define INV256   0.00390625f
#define INV512   0.001953125f
#define INV1024  0.0009765625f

typedef _Float16 half8 __attribute__((ext_vector_type(8)));
typedef __fp16   fp16x2 __attribute__((ext_vector_type(2)));
typedef float f32x4 __attribute__((ext_vector_type(4)));
typedef float f32x2 __attribute__((ext_vector_type(2)));

// DS-only scheduling fence (no instruction emitted, VMEM/VALU permeable).
#define FFT_SB() __builtin_amdgcn_sched_barrier(0x77)

// r17: packed butterfly (v_pk_add/mul/fma; (-im,re) folds into op_sel/neg).
__device__ __forceinline__ f32x2 cmulw(f32x2 d, float wr, float wi) {
    f32x2 sw; sw.x = -d.y; sw.y = d.x;
    return d * wr + sw * wi;
}
#define BFLYC(i0, i1, wr, wi) {            \
    f32x2 dif = zc[i0] - zc[i1];           \
    zc[i0] = zc[i0] + zc[i1];              \
    zc[i1] = cmulw(dif, (wr), (wi)); }

__device__ __forceinline__ unsigned pk_f16(float a, float b) {
    fp16x2 h = __builtin_amdgcn_cvt_pkrtz(a, b);
    union { fp16x2 h; unsigned u; } cvt; cvt.h = h;
    return cvt.u;
}

// r15-validated: v_sin/v_cos take REVOLUTIONS; pow2 args are exact, no range
// reduction needed. Error ~1e-6 abs, far below the f16 mag quantization.
__device__ __forceinline__ float2 twid(float rev) {
    return make_float2(__builtin_amdgcn_cosf(rev), __builtin_amdgcn_sinf(rev));
}

// ---------------------------------------------------------------------------
// Prep: tables + transposed, padded f16 mel weights. r16 sentinel-skip.
// (WIN/R tables still written for layout compat; stage1 no longer reads them.)
// ---------------------------------------------------------------------------
__global__ __launch_bounds__(256) void mfcc_prep(
    const float* __restrict__ mel_fb, float* __restrict__ ws, int use_sent)
{
    if (use_sent) {
        const unsigned* sw = (const unsigned*)ws;
        if (sw[WS_TOT] == SENT0 && sw[WS_TOT + 1] == SENT1) return;
    }

    const int idx = blockIdx.x * 256 + threadIdx.x;   // grid = 64 blocks

    _Float16* bt = (_Float16*)(ws + WS_BT);
    for (int i = idx; i < 48 * 544; i += 64 * 256) {
        int n = i / 544, k = i - n * 544;
        float v = (n < NMEL && k < 513) ? mel_fb[k * NMEL + n] : 0.0f;
        bt[i] = (_Float16)v;
    }

    if (idx < 640 + 512 + 520) {
        int i = idx;
        if (i < 640) {
            ws[WS_WIN + i] = 0.5f - 0.5f * cosf(2.0f * PI_F * (float)i / 640.0f);
        } else if (i < 1152) {
            int k = i - 640;
            float s, c;
            sincosf(-2.0f * PI_F * (float)k / 1024.0f, &s, &c);
            ((float2*)(ws + WS_R))[k] = make_float2(c, s);
        } else {
            int j = i - 1152;
            int m = j / 13, c0 = j - m * 13;
            float d    = 2.0f * cosf(PI_F * (2.0f * m + 1.0f) * (float)c0 / 80.0f);
            float lift = 1.0f + 11.0f * sinf(PI_F * (float)c0 / 22.0f);
            ws[WS_DT + j] = d * 0.11180339887498949f * lift;   // 1/sqrt(80)
        }
    }

    if (use_sent && idx == 0) {
        unsigned* sw = (unsigned*)ws;
        sw[WS_TOT]     = SENT0;
        sw[WS_TOT + 1] = SENT1;
    }
}

// ---------------------------------------------------------------------------
// Stage-1 helpers (inlined, statically indexed).
// ---------------------------------------------------------------------------
__device__ __forceinline__ void ldFrame(float2 (&x)[5], const float* __restrict__ wave,
                                        int frame, int L)
{
    const int b = frame / NFRAME;
    const int f = frame - b * NFRAME;
    const float2* xp = (const float2*)(wave + (size_t)b * NSAMP + (size_t)f * 320);
    #pragma unroll
    for (int j = 0; j < 5; ++j) x[j] = xp[L + 64 * j];
}

// phaseI with window + twA/twB/twC on the fly.
// winv[j] = (w[2n], w[2n+1]) at n = L+64j; w[i] = 0.5-0.5*cos_rev(i/640):
//   w[2n] = cos_rev(n/320), w[2n+1] = cos_rev(n/320 + 1/640).
// twA[j] = W^(2(L+64j)) -> rev = -L/512 - 0.125j (exact)
// twB[j] = W^(4(L+64j)) -> rev = -L/256 - 0.25j  (exact)
// twC    = W^(8L)       -> rev = -L/128          (exact)
__device__ __forceinline__ void phaseIc(f32x2 (&zc)[8], const float2 (&xv)[5], int L)
{
    const float nb = (float)L;
    #pragma unroll
    for (int j = 0; j < 8; ++j) { zc[j].x = 0.0f; zc[j].y = 0.0f; }
    #pragma unroll
    for (int j = 0; j < 5; ++j) {
        float n2 = (float)(L + 64 * j) * (1.0f / 320.0f);
        float wx = 0.5f - 0.5f * __builtin_amdgcn_cosf(n2);
        float wy = 0.5f - 0.5f * __builtin_amdgcn_cosf(n2 + (1.0f / 640.0f));
        zc[j].x = xv[j].x * wx;
        zc[j].y = xv[j].y * wy;
    }
    const float a0 = -nb * INV512;
    #pragma unroll
    for (int j = 0; j < 4; ++j) {
        float2 w = twid(a0 - 0.125f * (float)j);
        BFLYC(j, j + 4, w.x, w.y);                                      // 512
    }
    const float b0r = -nb * INV256;
    {
        float2 w0 = twid(b0r), w1 = twid(b0r - 0.25f);                  // 256
        BFLYC(0, 2, w0.x, w0.y); BFLYC(1, 3, w1.x, w1.y);
        BFLYC(4, 6, w0.x, w0.y); BFLYC(5, 7, w1.x, w1.y);
    }
    {
        float2 wc = twid(-nb * INV128);                                 // 128
        #pragma unroll
        for (int i0 = 0; i0 < 8; i0 += 2) BFLYC(i0, i0 + 1, wc.x, wc.y);
    }
}

// phaseII with twD/twE/twF on the fly:
// twD[j] = W^(128j+16s) -> rev = -s/64 - 0.125j; twE[j] -> -s/32 - 0.25j;
// twF = W^(64s) -> -s/16. (all exact)
__device__ __forceinline__ void phaseIIc(f32x2 (&zc)[8], const float4 (&q)[4], int s)
{
    zc[0].x = q[0].x; zc[0].y = q[0].y; zc[1].x = q[0].z; zc[1].y = q[0].w;
    zc[2].x = q[1].x; zc[2].y = q[1].y; zc[3].x = q[1].z; zc[3].y = q[1].w;
    zc[4].x = q[2].x; zc[4].y = q[2].y; zc[5].x = q[2].z; zc[5].y = q[2].w;
    zc[6].x = q[3].x; zc[6].y = q[3].y; zc[7].x = q[3].z; zc[7].y = q[3].w;
    const float fs = (float)s;
    const float d0 = -fs * INV64;
    #pragma unroll
    for (int j = 0; j < 4; ++j) {
        float2 w = twid(d0 - 0.125f * (float)j);
        BFLYC(j, j + 4, w.x, w.y);                                      // 64
    }
    const float e0 = -fs * INV32;
    {
        float2 w0 = twid(e0), w1 = twid(e0 - 0.25f);                    // 32
        BFLYC(0, 2, w0.x, w0.y); BFLYC(1, 3, w1.x, w1.y);
        BFLYC(4, 6, w0.x, w0.y); BFLYC(5, 7, w1.x, w1.y);
    }
    {
        float2 wf = twid(-fs * INV16);                                  // 16
        #pragma unroll
        for (int i0 = 0; i0 < 8; i0 += 2) BFLYC(i0, i0 + 1, wf.x, wf.y);
    }
}

__device__ __forceinline__ void phaseIII(f32x2 (&zc)[8], const float4 (&q)[4])
{
    zc[0].x = q[0].x; zc[0].y = q[0].y; zc[1].x = q[0].z; zc[1].y = q[0].w;
    zc[2].x = q[1].x; zc[2].y = q[1].y; zc[3].x = q[1].z; zc[3].y = q[1].w;
    zc[4].x = q[2].x; zc[4].y = q[2].y; zc[5].x = q[2].z; zc[5].y = q[2].w;
    zc[6].x = q[3].x; zc[6].y = q[3].y; zc[7].x = q[3].z; zc[7].y = q[3].w;
    const float C = 0.70710678118654752f;
    const float w8r[4] = { 1.0f,  C, 0.0f, -C };
    const float w8i[4] = { 0.0f, -C, -1.0f, -C };
    #pragma unroll
    for (int j = 0; j < 4; ++j) BFLYC(j, j + 4, w8r[j], w8i[j]);        // 8
    #pragma unroll
    for (int g = 0; g < 8; g += 4) {                                    // 4
        BFLYC(g + 0, g + 2, 1.0f, 0.0f);
        BFLYC(g + 1, g + 3, 0.0f, -1.0f);
    }
    #pragma unroll
    for (int i0 = 0; i0 < 8; i0 += 2) BFLYC(i0, i0 + 1, 1.0f, 0.0f);    // 2
}

__device__ __forceinline__ void wrEx1(float2* Z, const f32x2 (&zc)[8], int s, int a)
{
    #pragma unroll
    for (int j = 0; j < 8; ++j) Z[80 * j + 10 * s + a] = make_float2(zc[j].x, zc[j].y);
}

__device__ __forceinline__ void wrEx2(float2* Z, const f32x2 (&zc)[8], int s, int a)
{
    #pragma unroll
    for (int j = 0; j < 8; ++j) Z[80 * a + 10 * j + s] = make_float2(zc[j].x, zc[j].y);
}

__device__ __forceinline__ void wrEx3(float2* Z, const f32x2 (&zc)[8], int u)
{
    const int rev3t[8] = { 0, 4, 2, 6, 1, 5, 3, 7 };
    #pragma unroll
    for (int j = 0; j < 8; ++j) Z[80 * rev3t[j] + u] = make_float2(zc[j].x, zc[j].y);
}

__device__ __forceinline__ void rdEx(const float2* Z, int L, float4 (&q)[4])
{
    q[0] = *(const float4*)&Z[10 * L + 0];
    q[1] = *(const float4*)&Z[10 * L + 2];
    q[2] = *(const float4*)&Z[10 * L + 4];
    q[3] = *(const float4*)&Z[10 * L + 6];
}

__device__ __forceinline__ void rdMag(const float2* Z, int L,
    float4 (&aq)[4], float4 (&tq)[4], float2& b0)
{
    aq[0] = *(const float4*)&Z[10 * L + 0];
    aq[1] = *(const float4*)&Z[10 * L + 2];
    aq[2] = *(const float4*)&Z[10 * L + 4];
    aq[3] = *(const float4*)&Z[10 * L + 6];
    tq[0] = *(const float4*)&Z[630 - 10 * L + 0];   // i=0,1 (j=8,7)
    tq[1] = *(const float4*)&Z[630 - 10 * L + 2];   // i=2,3 (j=6,5)
    tq[2] = *(const float4*)&Z[630 - 10 * L + 4];   // i=4,5 (j=4,3)
    tq[3] = *(const float4*)&Z[630 - 10 * L + 6];   // i=6,7 (j=2,1)
    b0    = Z[640 - 10 * L];                        // j=0 (garbage if L==0)
}

// branchless + lane-0 fixup; hw sqrt; twS on the fly (r15-validated formula:
// rev = -L/128 - j/1024, exact).
__device__ __forceinline__ void magPhase(const float4 (&aq)[4], const float4 (&tq)[4],
    const float2 b0, const int L, uint4& mgpo, float& m512o)
{
    float Ax[8], Ay[8], Bx[8], By[8];
    Ax[0] = aq[0].x; Ay[0] = aq[0].y; Ax[1] = aq[0].z; Ay[1] = aq[0].w;
    Ax[2] = aq[1].x; Ay[2] = aq[1].y; Ax[3] = aq[1].z; Ay[3] = aq[1].w;
    Ax[4] = aq[2].x; Ay[4] = aq[2].y; Ax[5] = aq[2].z; Ay[5] = aq[2].w;
    Ax[6] = aq[3].x; Ay[6] = aq[3].y; Ax[7] = aq[3].z; Ay[7] = aq[3].w;
    Bx[0] = b0.x;    By[0] = b0.y;
    Bx[7] = tq[0].z; By[7] = tq[0].w;
    Bx[6] = tq[1].x; By[6] = tq[1].y;
    Bx[5] = tq[1].z; By[5] = tq[1].w;
    Bx[4] = tq[2].x; By[4] = tq[2].y;
    Bx[3] = tq[2].z; By[3] = tq[2].w;
    Bx[2] = tq[3].x; By[2] = tq[3].y;
    Bx[1] = tq[3].z; By[1] = tq[3].w;
    const float s0 = -(float)L * INV128;
    float mg[8];
    #pragma unroll
    for (int j = 0; j < 8; ++j) {
        float2 tws = twid(s0 - (float)j * INV1024);   // W^(8L+j)
        float xer = 0.5f * (Ax[j] + Bx[j]), xei = 0.5f * (Ay[j] - By[j]);
        float xo  = 0.5f * (Ay[j] + By[j]), xoi = -0.5f * (Ax[j] - Bx[j]);
        float xr = xer + tws.x * xo - tws.y * xoi;
        float xi = xei + tws.x * xoi + tws.y * xo;
        mg[j] = __builtin_amdgcn_sqrtf(xr * xr + xi * xi);
    }
    if (L == 0) {                        // bin k=0: X[0] = sum, m512 = alt-sum
        mg[0]  = fabsf(Ax[0] + Ay[0]);
        m512o  = fabsf(Ax[0] - Ay[0]);
    }
    mgpo.x = pk_f16(mg[0], mg[1]);
    mgpo.y = pk_f16(mg[2], mg[3]);
    mgpo.z = pk_f16(mg[4], mg[5]);
    mgpo.w = pk_f16(mg[6], mg[7]);
}

// ---------------------------------------------------------------------------
// Stage 1 — r18: occupancy round. Findings so far: wall is stall-bound (VALU
// 44%, DS ~25%, HBM 6%), and occupancy follows the VGPR tier model (<=64 VGPR
// -> 16 waves/CU, r11 measured 49%; 65..128 -> 8 waves/CU, measured ~19%).
// r15 paid TRANS but stayed at 104 VGPR (no cliff crossed); r11 forced 48 on
// a ~100-reg structure (spilled). r18 SHRINKS the structure first:
//  - single-frame loop (no 2-frame pipeline): -32 regs (TLP replaces ILP)
//  - ALL twiddles + window on the fly (r15-validated): -54 table regs
//  - mag written to a SEPARATE LDS tile immediately per frame: -16 regs
//    (LDS 20.5 -> 39.4 KB/block; still 4 blocks/CU at 160 KB pool)
//  - xv reloaded in place (no prefetch regs)
// then clamps with __launch_bounds__(256, 4). Peak live est. ~55-62.
// Tripwire: FETCH_SIZE must stay ~34 MB; ballooning = spills = revert.
// ---------------------------------------------------------------------------
__global__ __launch_bounds__(256, 4) void mfcc_stage1(
    const float* __restrict__ wave, const float* __restrict__ ws,
    float* __restrict__ out)
{
    // LDS layout: Z[4][640] float2 (20480) | 16B guard (lane0 wave3 reads
    // Z[640]) | mag[16][1104B] f16 tile (17664) | lm[16][40] f16 (1280)
    __shared__ __align__(16) char smem[20480 + 16 + 16 * 1104 + 16 * 40 * 2];
    char* magc = smem + 20496;
    _Float16* lm = (_Float16*)(smem + 20496 + 17664);

    const int tid = threadIdx.x;
    const int wv  = tid >> 6;
    const int L   = tid & 63;
    const int s   = L & 7;
    const int a   = L >> 3;

    float2* Z = (float2*)smem + wv * 640;            // wave-private FFT buffer

    // bit-reverse slot base for the final write, loop-invariant
    const int r6 = (int)(__brev((unsigned)L) >> 26);
    const int u  = r6 + 2 * (r6 >> 3);

    const int fbase = blockIdx.x * 16 + wv * 4;

    float2 xv[5];
    ldFrame(xv, wave, fbase, L);

    #pragma unroll 1
    for (int fi = 0; fi < 4; ++fi) {
        f32x2 zc[8];
        phaseIc(zc, xv, L);
        FFT_SB();
        wrEx1(Z, zc, s, a);
        FFT_SB();
        // xv dead now — reload next frame's samples in place (VMEM crosses
        // fences; latency covered by the rest of this frame's compute).
        if (fi < 3) ldFrame(xv, wave, fbase + fi + 1, L);
        float4 q[4];
        rdEx(Z, L, q);
        FFT_SB();
        phaseIIc(zc, q, s);
        wrEx2(Z, zc, s, a);
        FFT_SB();
        rdEx(Z, L, q);
        FFT_SB();
        phaseIII(zc, q);
        wrEx3(Z, zc, u);
        FFT_SB();
        float4 aq[4], tq[4]; float2 b0;
        rdMag(Z, L, aq, tq, b0);
        FFT_SB();
        uint4 mg; float m512 = 0.0f;
        magPhase(aq, tq, b0, L, mg, m512);
        // write this frame's row of the mag tile immediately (frees regs)
        char* mrow = magc + (wv * 4 + fi) * 1104;
        *(uint4*)(mrow + 16 * L) = mg;
        if (L < 20) {   // zero pad bins [512..552), bin 512 = m512
            unsigned v = (L == 0) ? pk_f16(m512, 0.0f) : 0u;
            *(unsigned*)(mrow + 1024 + 4 * L) = v;
        }
        FFT_SB();   // Z reads ordered before next frame's writes
    }

    __syncthreads();

    // ---- mel projection: D[16 frames][16 mels] per wave, K = 544 ----
    if (wv < 3) {
        const int nl = L & 15, qq = L >> 4;
        const char* ap = magc + nl * 1104 + qq * 16;               // A: frame rows
        const _Float16* btp = (const _Float16*)(ws + WS_BT)
                              + (size_t)(wv * 16 + nl) * 544 + qq * 8;
        f32x4 acc = {0.0f, 0.0f, 0.0f, 0.0f};
        #pragma unroll
        for (int kk = 0; kk < 17; ++kk) {
            half8 av = *(const half8*)(ap + kk * 64);
            half8 bv = *(const half8*)(btp + kk * 32);
            acc = __builtin_amdgcn_mfma_f32_16x16x32_f16(av, bv, acc, 0, 0, 0);
        }
        const int mel = wv * 16 + nl;
        if (mel < NMEL) {
            #pragma unroll
            for (int r = 0; r < 4; ++r) {
                int fl = qq * 4 + r;                // C/D: row=(lane>>4)*4+r
                lm[fl * NMEL + mel] = (_Float16)__logf(acc[r] + 1e-6f);
            }
        }
    }
    __syncthreads();

    // ---- DCT + scale + lifter, fp32: 208 threads = 16 frames x 13 ceps ----
    if (tid < 16 * NCEP) {
        const int fl = tid / NCEP, c = tid - fl * NCEP;
        float acc = 0.0f;
        #pragma unroll
        for (int m = 0; m < NMEL; ++m)
            acc += (float)lm[fl * NMEL + m] * ws[WS_DT + m * 13 + c];
        out[(size_t)(blockIdx.x * 16 + fl) * (3 * NCEP) + c] = acc;
    }
}

// ---------------------------------------------------------------------------
// Stage 2: per-batch deltas. r16: one WAVE per batch (4 per 256-thread block,
// grid 256); per-wave in-order DS replaces __syncthreads; 3 passes fused.
// ---------------------------------------------------------------------------
__global__ __launch_bounds__(256) void mfcc_stage2(float* __restrict__ out)
{
    #define TC (NFRAME * NCEP)   // 637
    __shared__ float xs [4][TC];
    __shared__ float d1s[4][TC];

    const int wv = threadIdx.x >> 6;
    const int L  = threadIdx.x & 63;
    const int b  = blockIdx.x * 4 + wv;

    float* xw  = xs[wv];
    float* d1w = d1s[wv];
    const size_t obase = (size_t)b * NFRAME * (3 * NCEP);

    // load mfccs into the wave's LDS slice
    for (int i = L; i < TC; i += 64) {
        const int t = i / NCEP, c = i - t * NCEP;
        xw[i] = out[obase + t * (3 * NCEP) + c];
    }
    FFT_SB();   // DS order: writes above precede reads below (in-order per wave)

    // d1 = delta(x), store + keep in LDS
    for (int i = L; i < TC; i += 64) {
        const int t = i / NCEP, c = i - t * NCEP;
        float acc = 0.0f;
        #pragma unroll
        for (int k = -2; k <= 2; ++k) {
            if (k == 0) continue;
            int tt = t + k;
            tt = tt < 0 ? 0 : (tt > NFRAME - 1 ? NFRAME - 1 : tt);
            acc += (float)k * xw[tt * NCEP + c];
        }
        float d1 = acc * 0.1f;
        d1w[i] = d1;
        out[obase + t * (3 * NCEP) + NCEP + c] = d1;
    }
    FFT_SB();

    // d2 = delta(d1), store
    for (int i = L; i < TC; i += 64) {
        const int t = i / NCEP, c = i - t * NCEP;
        float acc = 0.0f;
        #pragma unroll
        for (int k = -2; k <= 2; ++k) {
            if (k == 0) continue;
            int tt = t + k;
            tt = tt < 0 ? 0 : (tt > NFRAME - 1 ? NFRAME - 1 : tt);
            acc += (float)k * d1w[tt * NCEP + c];
        }
        out[obase + t * (3 * NCEP) + 2 * NCEP + c] = acc * 0.1f;
    }
    #undef TC
}

extern "C" void kernel_launch(void* const* d_in, const int* in_sizes, int n_in,
                              void* d_out, int out_size, void* d_ws, size_t ws_size,
                              hipStream_t stream)
{
    const float* wave   = (const float*)d_in[0];   // [1024][16000] f32
    const float* mel_fb = (const float*)d_in[1];   // [513][40] f32
    float* out = (float*)d_out;                    // [1024][49][39][1] f32
    float* ws  = (float*)d_ws;

    // sentinel slot needs (WS_TOT+2) floats of workspace
    const int use_sent = (ws_size >= (size_t)(WS_TOT + 2) * 4) ? 1 : 0;

    mfcc_prep<<<64, 256, 0, stream>>>(mel_fb, ws, use_sent);
    mfcc_stage1<<<(BATCH * NFRAME) / 16, 256, 0, stream>>>(wave, ws, out);
    mfcc_stage2<<<BATCH / 4, 256, 0, stream>>>(out);
}

// Round 11
// 152.544 us; speedup vs baseline: 1.0379x; 1.0379x over previous
//
#include <hip/hip_runtime.h>
#include <math.h>

#define NMEL   40
#define NCEP   13
#define BATCH  1024
#define NSAMP  16000
#define NFRAME 49
#define PI_F   3.14159265358979323846f

// d_ws float layout
#define WS_WIN  0        // 640 floats: Hann window
#define WS_R    640      // 512 float2: W_1024^k, k=0..511 (1024 floats)
#define WS_DT   1664     // 520 floats: DCT * 1/sqrt(80) * lifter, [40][13]
#define WS_BT   2184     // f16 area: Bt[48][544] mel weights transposed (13056 floats)
#define WS_TOT  15240

typedef _Float16 half8 __attribute__((ext_vector_type(8)));
typedef __fp16   fp16x2 __attribute__((ext_vector_type(2)));
typedef float f32x4 __attribute__((ext_vector_type(4)));

// DS-only scheduling fence (no instruction emitted, VMEM/VALU permeable).
// mask 0x77 = ALU|VALU|SALU|VMEM may cross; DS bits unset -> ds_* stay ordered.
#define FFT_SB() __builtin_amdgcn_sched_barrier(0x77)

// radix-2 DIF butterfly on register arrays zr/zi (visible via reference alias)
#define BFLY(i0, i1, wr, wi) {                        \
    float tr = zr[i0] - zr[i1], ti = zi[i0] - zi[i1]; \
    zr[i0] += zr[i1]; zi[i0] += zi[i1];               \
    zr[i1] = tr*(wr) - ti*(wi);                       \
    zi[i1] = tr*(wi) + ti*(wr); }

__device__ __forceinline__ unsigned pk_f16(float a, float b) {
    fp16x2 h = __builtin_amdgcn_cvt_pkrtz(a, b);
    union { fp16x2 h; unsigned u; } cvt; cvt.h = h;
    return cvt.u;
}

// ---------------------------------------------------------------------------
// Prep: window / twiddle / DCT tables + transposed, padded f16 mel weights.
// ---------------------------------------------------------------------------
__global__ __launch_bounds__(256) void mfcc_prep(
    const float* __restrict__ mel_fb, float* __restrict__ ws)
{
    const int idx = blockIdx.x * 256 + threadIdx.x;   // grid = 64 blocks

    _Float16* bt = (_Float16*)(ws + WS_BT);
    for (int i = idx; i < 48 * 544; i += 64 * 256) {
        int n = i / 544, k = i - n * 544;
        float v = (n < NMEL && k < 513) ? mel_fb[k * NMEL + n] : 0.0f;
        bt[i] = (_Float16)v;
    }

    if (idx < 640 + 512 + 520) {
        int i = idx;
        if (i < 640) {
            ws[WS_WIN + i] = 0.5f - 0.5f * cosf(2.0f * PI_F * (float)i / 640.0f);
        } else if (i < 1152) {
            int k = i - 640;
            float s, c;
            sincosf(-2.0f * PI_F * (float)k / 1024.0f, &s, &c);
            ((float2*)(ws + WS_R))[k] = make_float2(c, s);
        } else {
            int j = i - 1152;
            int m = j / 13, c0 = j - m * 13;
            float d    = 2.0f * cosf(PI_F * (2.0f * m + 1.0f) * (float)c0 / 80.0f);
            float lift = 1.0f + 11.0f * sinf(PI_F * (float)c0 / 22.0f);
            ws[WS_DT + j] = d * 0.11180339887498949f * lift;   // 1/sqrt(80)
        }
    }
}

// ---------------------------------------------------------------------------
// Stage-1 helper phases (all fully inlined; arrays statically indexed).
// ---------------------------------------------------------------------------
__device__ __forceinline__ void ldFrame(float2 (&x)[5], const float* __restrict__ wave,
                                        int frame, int L)
{
    const int b = frame / NFRAME;
    const int f = frame - b * NFRAME;
    const float2* xp = (const float2*)(wave + (size_t)b * NSAMP + (size_t)f * 320);
    #pragma unroll
    for (int j = 0; j < 5; ++j) x[j] = xp[L + 64 * j];
}

__device__ __forceinline__ void phaseI(float (&zr)[8], float (&zi)[8],
    const float2 (&xv)[5], const float2 (&winv)[5],
    const float2 (&twA)[4], const float2 (&twB)[2], const float2 twC)
{
    #pragma unroll
    for (int j = 0; j < 8; ++j) { zr[j] = 0.0f; zi[j] = 0.0f; }
    #pragma unroll
    for (int j = 0; j < 5; ++j) { zr[j] = xv[j].x * winv[j].x; zi[j] = xv[j].y * winv[j].y; }
    #pragma unroll
    for (int j = 0; j < 4; ++j) BFLY(j, j + 4, twA[j].x, twA[j].y);     // 512
    #pragma unroll
    for (int g = 0; g < 8; g += 4) {                                    // 256
        #pragma unroll
        for (int j = 0; j < 2; ++j) BFLY(g + j, g + j + 2, twB[j].x, twB[j].y);
    }
    #pragma unroll
    for (int i0 = 0; i0 < 8; i0 += 2) BFLY(i0, i0 + 1, twC.x, twC.y);   // 128
}

__device__ __forceinline__ void phaseII(float (&zr)[8], float (&zi)[8],
    const float4 (&q)[4],
    const float2 (&twD)[4], const float2 (&twE)[2], const float2 twF)
{
    zr[0] = q[0].x; zi[0] = q[0].y; zr[1] = q[0].z; zi[1] = q[0].w;
    zr[2] = q[1].x; zi[2] = q[1].y; zr[3] = q[1].z; zi[3] = q[1].w;
    zr[4] = q[2].x; zi[4] = q[2].y; zr[5] = q[2].z; zi[5] = q[2].w;
    zr[6] = q[3].x; zi[6] = q[3].y; zr[7] = q[3].z; zi[7] = q[3].w;
    #pragma unroll
    for (int j = 0; j < 4; ++j) BFLY(j, j + 4, twD[j].x, twD[j].y);     // 64
    #pragma unroll
    for (int g = 0; g < 8; g += 4) {                                    // 32
        #pragma unroll
        for (int j = 0; j < 2; ++j) BFLY(g + j, g + j + 2, twE[j].x, twE[j].y);
    }
    #pragma unroll
    for (int i0 = 0; i0 < 8; i0 += 2) BFLY(i0, i0 + 1, twF.x, twF.y);   // 16
}

__device__ __forceinline__ void phaseIII(float (&zr)[8], float (&zi)[8],
    const float4 (&q)[4])
{
    zr[0] = q[0].x; zi[0] = q[0].y; zr[1] = q[0].z; zi[1] = q[0].w;
    zr[2] = q[1].x; zi[2] = q[1].y; zr[3] = q[1].z; zi[3] = q[1].w;
    zr[4] = q[2].x; zi[4] = q[2].y; zr[5] = q[2].z; zi[5] = q[2].w;
    zr[6] = q[3].x; zi[6] = q[3].y; zr[7] = q[3].z; zi[7] = q[3].w;
    const float C = 0.70710678118654752f;
    const float w8r[4] = { 1.0f,  C, 0.0f, -C };
    const float w8i[4] = { 0.0f, -C, -1.0f, -C };
    #pragma unroll
    for (int j = 0; j < 4; ++j) BFLY(j, j + 4, w8r[j], w8i[j]);         // 8
    #pragma unroll
    for (int g = 0; g < 8; g += 4) {                                    // 4
        BFLY(g + 0, g + 2, 1.0f, 0.0f);
        BFLY(g + 1, g + 3, 0.0f, -1.0f);
    }
    #pragma unroll
    for (int i0 = 0; i0 < 8; i0 += 2) BFLY(i0, i0 + 1, 1.0f, 0.0f);     // 2
}

__device__ __forceinline__ void wrEx1(float2* Z, const float (&zr)[8], const float (&zi)[8],
                                      int s, int a)
{
    #pragma unroll
    for (int j = 0; j < 8; ++j) Z[80 * j + 10 * s + a] = make_float2(zr[j], zi[j]);
}

__device__ __forceinline__ void wrEx2(float2* Z, const float (&zr)[8], const float (&zi)[8],
                                      int s, int a)
{
    #pragma unroll
    for (int j = 0; j < 8; ++j) Z[80 * a + 10 * j + s] = make_float2(zr[j], zi[j]);
}

__device__ __forceinline__ void wrEx3(float2* Z, const float (&zr)[8], const float (&zi)[8],
                                      int u)
{
    const int rev3t[8] = { 0, 4, 2, 6, 1, 5, 3, 7 };
    #pragma unroll
    for (int j = 0; j < 8; ++j) Z[80 * rev3t[j] + u] = make_float2(zr[j], zi[j]);
}

__device__ __forceinline__ void rdEx(const float2* Z, int L, float4 (&q)[4])
{
    q[0] = *(const float4*)&Z[10 * L + 0];
    q[1] = *(const float4*)&Z[10 * L + 2];
    q[2] = *(const float4*)&Z[10 * L + 4];
    q[3] = *(const float4*)&Z[10 * L + 6];
}

__device__ __forceinline__ void rdMag(const float2* Z, int L,
    float4 (&aq)[4], float4 (&tq)[4], float2& b0)
{
    aq[0] = *(const float4*)&Z[10 * L + 0];
    aq[1] = *(const float4*)&Z[10 * L + 2];
    aq[2] = *(const float4*)&Z[10 * L + 4];
    aq[3] = *(const float4*)&Z[10 * L + 6];
    tq[0] = *(const float4*)&Z[630 - 10 * L + 0];   // i=0,1 (j=8,7)
    tq[1] = *(const float4*)&Z[630 - 10 * L + 2];   // i=2,3 (j=6,5)
    tq[2] = *(const float4*)&Z[630 - 10 * L + 4];   // i=4,5 (j=4,3)
    tq[3] = *(const float4*)&Z[630 - 10 * L + 6];   // i=6,7 (j=2,1)
    b0    = Z[640 - 10 * L];                        // j=0 (garbage if L==0)
}

// r14: branchless general path for all 8 bins + single lane-0 fixup (the old
// per-j `if (k==0)` kept 8 compares + dual paths live). sqrt via
// __builtin_amdgcn_sqrtf (1x v_sqrt_f32, ~1ulp; absmax budget 0.25 is safe)
// instead of libm's correctly-rounded multi-instruction sequence.
__device__ __forceinline__ void magPhase(const float4 (&aq)[4], const float4 (&tq)[4],
    const float2 b0, const float2 (&twS)[8], const int L, uint4& mgpo, float& m512o)
{
    float Ax[8], Ay[8], Bx[8], By[8];
    Ax[0] = aq[0].x; Ay[0] = aq[0].y; Ax[1] = aq[0].z; Ay[1] = aq[0].w;
    Ax[2] = aq[1].x; Ay[2] = aq[1].y; Ax[3] = aq[1].z; Ay[3] = aq[1].w;
    Ax[4] = aq[2].x; Ay[4] = aq[2].y; Ax[5] = aq[2].z; Ay[5] = aq[2].w;
    Ax[6] = aq[3].x; Ay[6] = aq[3].y; Ax[7] = aq[3].z; Ay[7] = aq[3].w;
    Bx[0] = b0.x;    By[0] = b0.y;
    Bx[7] = tq[0].z; By[7] = tq[0].w;
    Bx[6] = tq[1].x; By[6] = tq[1].y;
    Bx[5] = tq[1].z; By[5] = tq[1].w;
    Bx[4] = tq[2].x; By[4] = tq[2].y;
    Bx[3] = tq[2].z; By[3] = tq[2].w;
    Bx[2] = tq[3].x; By[2] = tq[3].y;
    Bx[1] = tq[3].z; By[1] = tq[3].w;
    float mg[8];
    #pragma unroll
    for (int j = 0; j < 8; ++j) {
        float xer = 0.5f * (Ax[j] + Bx[j]), xei = 0.5f * (Ay[j] - By[j]);
        float xo  = 0.5f * (Ay[j] + By[j]), xoi = -0.5f * (Ax[j] - Bx[j]);
        float xr = xer + twS[j].x * xo - twS[j].y * xoi;
        float xi = xei + twS[j].x * xoi + twS[j].y * xo;
        mg[j] = __builtin_amdgcn_sqrtf(xr * xr + xi * xi);
    }
    if (L == 0) {                        // bin k=0: X[0] = sum, m512 = alt-sum
        mg[0]  = fabsf(Ax[0] + Ay[0]);
        m512o  = fabsf(Ax[0] - Ay[0]);
    }
    mgpo.x = pk_f16(mg[0], mg[1]);
    mgpo.y = pk_f16(mg[2], mg[3]);
    mgpo.z = pk_f16(mg[4], mg[5]);
    mgpo.w = pk_f16(mg[6], mg[7]);
}

// ---------------------------------------------------------------------------
// Stage 1: 16 frames per block (4 waves x 2 PAIRS of pipelined FFTs).
// r10: slot(x) = x + 2*(x>>3) padding; writes <=2-way-conflict-free, reads
// lane-contiguous 16B-aligned ds_read_b128.
// r11/r12: DS-only sched_barrier fences + sample prefetch, plain bounds.
// r13: 2-frame software pipeline per wave, single Z buffer (in-order DS).
// r14: pair loop NOT unrolled (#pragma unroll 1): halves code size, gains
// back-edge I$ reuse. mgp/m512 rotate through NAMED registers at the loop
// tail (runtime-indexed arrays would go to scratch — rule #20).
// r21: byte-exact resubmission of the r14 source (verified 151.97 us total,
// absmax 0.25). r19/r20 both failed NaN (r19: unverifiable packed asm;
// r20: no mechanism found) — after two unexplained failures the rule is
// resubmit known-good with zero new variables.
// ---------------------------------------------------------------------------
__global__ __launch_bounds__(256) void mfcc_stage1(
    const float* __restrict__ wave, const float* __restrict__ ws,
    float* __restrict__ out)
{
    // LDS: float2 Z[4][640] (20480 B) overlaid by f16 mag[16][552] (17664 B);
    // lm[16][40] f16 (1280 B) lives at +17664 (dead space above mag tile).
    // +16 B guard: lane0's don't-care Z[640-0] read from wave 3.
    __shared__ __align__(16) char smem[4 * 640 * 8 + 16];
    char* smemc = smem;
    _Float16* lm = (_Float16*)(smem + 16 * 1104);    // [16][40] f16 @ 17664

    const int tid = threadIdx.x;
    const int wv  = tid >> 6;
    const int L   = tid & 63;
    const int s   = L & 7;
    const int a   = L >> 3;

    float2* Z = (float2*)smem + wv * 640;            // wave-private FFT buffer
    const float2* R   = (const float2*)(ws + WS_R);
    const float2* win = (const float2*)(ws + WS_WIN);

    // ---- hoist all loop-invariant tables into registers (once per wave) ----
    float2 twA[4], twB[2], twC, twD[4], twE[2], twF, twS[8], winv[5];
    #pragma unroll
    for (int j = 0; j < 4; ++j) twA[j] = R[2 * (L + 64 * j)];
    #pragma unroll
    for (int j = 0; j < 2; ++j) twB[j] = R[4 * (L + 64 * j)];
    twC = R[8 * L];
    #pragma unroll
    for (int j = 0; j < 4; ++j) twD[j] = R[128 * j + 16 * s];
    #pragma unroll
    for (int j = 0; j < 2; ++j) twE[j] = R[256 * j + 32 * s];
    twF = R[64 * s];
    #pragma unroll
    for (int j = 0; j < 8; ++j) twS[j] = R[8 * L + j];   // real-split W_1024^k
    #pragma unroll
    for (int j = 0; j < 5; ++j) winv[j] = win[L + 64 * j];

    // bit-reverse slot base for the final write, loop-invariant
    const int r6 = (int)(__brev((unsigned)L) >> 26);
    const int u  = r6 + 2 * (r6 >> 3);

    // per-frame packed f16 magnitudes, rotated through named regs (no dynamic
    // indexing -> no scratch). After 2 iterations: mgp0..3 = frames 0..3.
    uint4 mgp0, mgp1, mgp2, mgp3;
    float m5120 = 0.0f, m5121 = 0.0f, m5122 = 0.0f, m5123 = 0.0f;

    const int fbase = blockIdx.x * 16 + wv * 4;

    // prefetch pair 0's samples
    float2 xA[5], xB[5];
    ldFrame(xA, wave, fbase + 0, L);
    ldFrame(xB, wave, fbase + 1, L);

    #pragma unroll 1
    for (int p = 0; p < 2; ++p) {
        // prefetch next pair during this pair's compute (VMEM, fence-permeable)
        float2 xA2[5], xB2[5];
        if (p == 0) {
            ldFrame(xA2, wave, fbase + 2, L);
            ldFrame(xB2, wave, fbase + 3, L);
        }

        float zrA[8], ziA[8], zrB[8], ziB[8];
        float4 qA[4], qB[4];

        // ---- exchange-1 round ----
        phaseI(zrA, ziA, xA, winv, twA, twB, twC);
        FFT_SB();
        wrEx1(Z, zrA, ziA, s, a);
        FFT_SB();
        rdEx(Z, L, qA);                 // rd1A: latency covered by phaseI(B)
        FFT_SB();
        phaseI(zrB, ziB, xB, winv, twA, twB, twC);
        wrEx1(Z, zrB, ziB, s, a);       // DS order: after rd1A ✓
        FFT_SB();
        rdEx(Z, L, qB);                 // rd1B: covered by phaseII(A)
        FFT_SB();

        // ---- exchange-2 round ----
        phaseII(zrA, ziA, qA, twD, twE, twF);
        wrEx2(Z, zrA, ziA, s, a);       // after rd1B ✓
        FFT_SB();
        rdEx(Z, L, qA);                 // rd2A: covered by phaseII(B)
        FFT_SB();
        phaseII(zrB, ziB, qB, twD, twE, twF);
        wrEx2(Z, zrB, ziB, s, a);       // after rd2A ✓
        FFT_SB();
        rdEx(Z, L, qB);                 // rd2B: covered by phaseIII(A)
        FFT_SB();

        // ---- final bit-reverse round + real-split reads ----
        phaseIII(zrA, ziA, qA);
        wrEx3(Z, zrA, ziA, u);          // after rd2B ✓
        FFT_SB();
        float4 aqA[4], tqA[4]; float2 b0A;
        rdMag(Z, L, aqA, tqA, b0A);     // rd3A: covered by phaseIII(B)
        FFT_SB();
        phaseIII(zrB, ziB, qB);
        wrEx3(Z, zrB, ziB, u);          // after rd3A ✓
        FFT_SB();
        float4 aqB[4], tqB[4]; float2 b0B;
        rdMag(Z, L, aqB, tqB, b0B);     // rd3B: covered by magPhase(A)
        FFT_SB();

        // ---- magnitudes ----
        uint4 mgA, mgB;
        float mA = 0.0f, mB = 0.0f;
        magPhase(aqA, tqA, b0A, twS, L, mgA, mA);
        magPhase(aqB, tqB, b0B, twS, L, mgB, mB);
        FFT_SB();   // Z reads ordered before next pair's writes

        // rotate the result queue (static register moves)
        mgp0 = mgp2;  mgp1 = mgp3;  mgp2 = mgA;  mgp3 = mgB;
        m5120 = m5122; m5121 = m5123; m5122 = mA; m5123 = mB;

        if (p == 0) {
            #pragma unroll
            for (int j = 0; j < 5; ++j) { xA[j] = xA2[j]; xB[j] = xB2[j]; }
        }
    }

    // ---- all FFTs done: overlay mag tile [16][552] f16 onto smem ----
    __syncthreads();
    {
        const int row = wv * 4;
        *(uint4*)(smemc + (row + 0) * 1104 + 16 * L) = mgp0;
        *(uint4*)(smemc + (row + 1) * 1104 + 16 * L) = mgp1;
        *(uint4*)(smemc + (row + 2) * 1104 + 16 * L) = mgp2;
        *(uint4*)(smemc + (row + 3) * 1104 + 16 * L) = mgp3;
        if (L < 20) {   // zero pad bins [512..552), bin 512 = m512
            unsigned v0 = (L == 0) ? pk_f16(m5120, 0.0f) : 0u;
            unsigned v1 = (L == 0) ? pk_f16(m5121, 0.0f) : 0u;
            unsigned v2 = (L == 0) ? pk_f16(m5122, 0.0f) : 0u;
            unsigned v3 = (L == 0) ? pk_f16(m5123, 0.0f) : 0u;
            *(unsigned*)(smemc + (row + 0) * 1104 + 1024 + 4 * L) = v0;
            *(unsigned*)(smemc + (row + 1) * 1104 + 1024 + 4 * L) = v1;
            *(unsigned*)(smemc + (row + 2) * 1104 + 1024 + 4 * L) = v2;
            *(unsigned*)(smemc + (row + 3) * 1104 + 1024 + 4 * L) = v3;
        }
    }
    __syncthreads();

    // ---- mel projection: D[16 frames][16 mels] per wave, K = 544 ----
    if (wv < 3) {
        const int nl = L & 15, q = L >> 4;
        const char* ap = smemc + nl * 1104 + q * 16;                // A: frame rows
        const _Float16* btp = (const _Float16*)(ws + WS_BT)
                              + (size_t)(wv * 16 + nl) * 544 + q * 8;
        f32x4 acc = {0.0f, 0.0f, 0.0f, 0.0f};
        #pragma unroll
        for (int kk = 0; kk < 17; ++kk) {
            half8 av = *(const half8*)(ap + kk * 64);
            half8 bv = *(const half8*)(btp + kk * 32);
            acc = __builtin_amdgcn_mfma_f32_16x16x32_f16(av, bv, acc, 0, 0, 0);
        }
        const int mel = wv * 16 + nl;
        if (mel < NMEL) {
            #pragma unroll
            for (int r = 0; r < 4; ++r) {
                int fl = q * 4 + r;                 // C/D: row=(lane>>4)*4+r
                lm[fl * NMEL + mel] = (_Float16)__logf(acc[r] + 1e-6f);
            }
        }
    }
    __syncthreads();

    // ---- DCT + scale + lifter, fp32: 208 threads = 16 frames x 13 ceps ----
    if (tid < 16 * NCEP) {
        const int fl = tid / NCEP, c = tid - fl * NCEP;
        float acc = 0.0f;
        #pragma unroll
        for (int m = 0; m < NMEL; ++m)
            acc += (float)lm[fl * NMEL + m] * ws[WS_DT + m * 13 + c];
        out[(size_t)(blockIdx.x * 16 + fl) * (3 * NCEP) + c] = acc;
    }
}

// ---------------------------------------------------------------------------
// Stage 2: per-batch deltas.
// ---------------------------------------------------------------------------
__global__ __launch_bounds__(128) void mfcc_stage2(float* __restrict__ out)
{
    __shared__ float x [NFRAME * NCEP];
    __shared__ float d1[NFRAME * NCEP];

    const int b = blockIdx.x;
    const int tid = threadIdx.x;
    const int TC = NFRAME * NCEP;

    for (int i = tid; i < TC; i += 128) {
        const int t = i / NCEP, c = i - t * NCEP;
        x[i] = out[((size_t)b * NFRAME + t) * (3 * NCEP) + c];
    }
    __syncthreads();

    for (int i = tid; i < TC; i += 128) {
        const int t = i / NCEP, c = i - t * NCEP;
        float acc = 0.0f;
        #pragma unroll
        for (int k = -2; k <= 2; ++k) {
            if (k == 0) continue;
            int tt = t + k;
            tt = tt < 0 ? 0 : (tt > NFRAME - 1 ? NFRAME - 1 : tt);
            acc += (float)k * x[tt * NCEP + c];
        }
        d1[i] = acc * 0.1f;
    }
    __syncthreads();

    for (int i = tid; i < TC; i += 128) {
        const int t = i / NCEP, c = i - t * NCEP;
        float acc = 0.0f;
        #pragma unroll
        for (int k = -2; k <= 2; ++k) {
            if (k == 0) continue;
            int tt = t + k;
            tt = tt < 0 ? 0 : (tt > NFRAME - 1 ? NFRAME - 1 : tt);
            acc += (float)k * d1[tt * NCEP + c];
        }
        const size_t base = ((size_t)b * NFRAME + t) * (3 * NCEP);
        out[base +     NCEP + c] = d1[i];
        out[base + 2 * NCEP + c] = acc * 0.1f;
    }
}

extern "C" void kernel_launch(void* const* d_in, const int* in_sizes, int n_in,
                              void* d_out, int out_size, void* d_ws, size_t ws_size,
                              hipStream_t stream)
{
    const float* wave   = (const float*)d_in[0];   // [1024][16000] f32
    const float* mel_fb = (const float*)d_in[1];   // [513][40] f32
    float* out = (float*)d_out;                    // [1024][49][39][1] f32
    float* ws  = (float*)d_ws;

    mfcc_prep<<<64, 256, 0, stream>>>(mel_fb, ws);
    mfcc_stage1<<<(BATCH * NFRAME) / 16, 256, 0, stream>>>(wave, ws, out);
    mfcc_stage2<<<BATCH, 128, 0, stream>>>(out);
}